// Round 1
// baseline (24315.013 us; speedup 1.0000x reference)
//
#include <hip/hip_runtime.h>

// NeuralCDE RK4 integrator, fp32 VALU baseline.
// B=8192 batches are independent -> persistent kernel: each WG owns NB=32
// batches for the full 255-step scan. Per stage:
//   phase1: pre = z @ W1 + b1 ; h = tanh(pre)        (32 -> 128)
//   phase2: g = h @ W2 + b2 ; k = sum_i g[.,o,i]*dx_i (128 -> 192 -> 32)
// RK4: k1..k4 with dx evaluated at f = {0, dt/2, dt/2, dt}.

constexpr int B_TOT  = 8192;
constexpr int L      = 256;
constexpr int CIN    = 6;
constexpr int H      = 32;
constexpr int MID    = 128;
constexpr int NSTEPS = L - 1;   // 255
constexpr int NB     = 32;      // batches per workgroup
constexpr int WG     = 512;     // 8 waves
constexpr int HPAD   = 132;     // h row pad: 132 % 32 == 4 -> 4-way (1.58x) on b128, 16B aligned
constexpr int ZPAD   = 33;      // z row pad: odd -> conflict-free scalar access

__global__ __launch_bounds__(WG, 2)
void cde_rk4_kernel(const float* __restrict__ times,
                    const float* __restrict__ coeff_b,
                    const float* __restrict__ coeff_c,
                    const float* __restrict__ coeff_d,
                    const float* __restrict__ W1g,
                    const float* __restrict__ b1g,
                    const float* __restrict__ W2g,
                    const float* __restrict__ b2g,
                    const float* __restrict__ Wlg,
                    const float* __restrict__ blg,
                    float* __restrict__ out)
{
    __shared__ float sW1[H][MID];        // 16 KB
    __shared__ float sB1[MID];
    __shared__ float sB2[H * CIN];
    __shared__ float sHh[NB][HPAD];      // 16.5 KB
    __shared__ float sZb[NB][ZPAD];      // z at step start
    __shared__ float sZc[NB][ZPAD];      // current stage input z
    __shared__ float sZa[NB][ZPAD];      // accumulated next z
    __shared__ float sDx[3][NB][8];      // dx at f=0, dt/2, dt

    const int tid = threadIdx.x;
    const int b0  = blockIdx.x * NB;

    // ---- one-time staging ----
    for (int i = tid; i < H * MID; i += WG) sW1[i >> 7][i & 127] = W1g[i];
    for (int i = tid; i < MID; i += WG)     sB1[i] = b1g[i];
    for (int i = tid; i < H * CIN; i += WG) sB2[i] = b2g[i];
    for (int i = tid; i < NB * ZPAD; i += WG) {
        (&sZb[0][0])[i] = 0.f; (&sZc[0][0])[i] = 0.f; (&sZa[0][0])[i] = 0.f;
    }
    __syncthreads();

    const int bl_ = tid & 31;   // batch within WG (per-lane)
    const int grp = tid >> 5;   // 0..15: P1 -> 8 mids, P2 -> o-pair {2*grp, 2*grp+1}
    const float* w2base = W2g + grp * 12;   // &W2[0][grp*12], rows stride 192

    for (int t = 0; t < NSTEPS; ++t) {
        const float dt = times[t + 1] - times[t];
        if (tid < NB * CIN) {
            const int bb = tid / CIN, ii = tid - bb * CIN;
            const size_t off = ((size_t)(b0 + bb) * NSTEPS + t) * CIN + ii;
            const float vb = coeff_b[off], vc = coeff_c[off], vd = coeff_d[off];
            const float f1 = 0.5f * dt;
            sDx[0][bb][ii] = vb;                              // dX(0)
            sDx[1][bb][ii] = vb + vc * f1 + vd * f1 * f1;     // dX(dt/2)
            sDx[2][bb][ii] = vb + vc * dt + vd * dt * dt;     // dX(dt)
        }
        __syncthreads();

        for (int s = 0; s < 4; ++s) {
            // ---------- phase 1: h = tanh(z @ W1 + b1) ----------
            float acc1[8];
            #pragma unroll
            for (int q = 0; q < 8; ++q) acc1[q] = sB1[grp * 8 + q];
            #pragma unroll
            for (int j = 0; j < H; ++j) {
                const float zv = sZc[bl_][j];
                #pragma unroll
                for (int q = 0; q < 8; ++q) acc1[q] += zv * sW1[j][grp * 8 + q];
            }
            #pragma unroll
            for (int q = 0; q < 8; ++q) {
                const float e = __expf(2.f * acc1[q]);        // tanh(x)=1-2/(e^{2x}+1)
                sHh[bl_][grp * 8 + q] = 1.f - 2.f / (e + 1.f);
            }
            __syncthreads();

            // ---------- phase 2: k[b][o] for o-pair, W2 streamed from L1/L2 ----------
            float a20[6], a21[6];
            #pragma unroll
            for (int i = 0; i < 6; ++i) {
                a20[i] = sB2[grp * 12 + i];
                a21[i] = sB2[grp * 12 + 6 + i];
            }
            #pragma unroll 2
            for (int m4 = 0; m4 < MID; m4 += 4) {
                const float4 hv = *(const float4*)&sHh[bl_][m4];
                const float hs[4] = {hv.x, hv.y, hv.z, hv.w};
                #pragma unroll
                for (int mm = 0; mm < 4; ++mm) {
                    const float4* w2q = (const float4*)(w2base + (size_t)(m4 + mm) * (H * CIN));
                    const float4 wa = w2q[0], wb = w2q[1], wc = w2q[2];
                    const float hm = hs[mm];
                    a20[0] += hm * wa.x; a20[1] += hm * wa.y; a20[2] += hm * wa.z; a20[3] += hm * wa.w;
                    a20[4] += hm * wb.x; a20[5] += hm * wb.y;
                    a21[0] += hm * wb.z; a21[1] += hm * wb.w;
                    a21[2] += hm * wc.x; a21[3] += hm * wc.y; a21[4] += hm * wc.z; a21[5] += hm * wc.w;
                }
            }
            const int dsel = (s == 0) ? 0 : ((s == 3) ? 2 : 1);
            float k0 = 0.f, k1 = 0.f;
            #pragma unroll
            for (int i = 0; i < 6; ++i) {
                const float dx = sDx[dsel][bl_][i];
                k0 += a20[i] * dx;
                k1 += a21[i] * dx;
            }

            // ---------- RK4 state update (each (b,o) owned by one thread) ----------
            const int o0 = grp * 2, o1 = o0 + 1;
            const float ws = (s == 0 || s == 3) ? dt * (1.f / 6.f) : dt * (1.f / 3.f);
            const float za0 = sZa[bl_][o0] + ws * k0;
            const float za1 = sZa[bl_][o1] + ws * k1;
            sZa[bl_][o0] = za0; sZa[bl_][o1] = za1;
            if (s < 3) {
                const float al = (s == 2) ? dt : 0.5f * dt;
                sZc[bl_][o0] = sZb[bl_][o0] + al * k0;
                sZc[bl_][o1] = sZb[bl_][o1] + al * k1;
            } else {
                sZb[bl_][o0] = za0; sZb[bl_][o1] = za1;
                sZc[bl_][o0] = za0; sZc[bl_][o1] = za1;
            }
            __syncthreads();
        }
    }

    // ---------- readout: out = zT @ Wl + bl ----------
    if (tid < NB * CIN) {
        const int bb = tid & 31, cc = tid >> 5;   // 32 batches x 6 channels
        float acc = blg[cc];
        #pragma unroll
        for (int j = 0; j < H; ++j) acc += sZb[bb][j] * Wlg[j * CIN + cc];
        out[(size_t)(b0 + bb) * CIN + cc] = acc;
    }
}

extern "C" void kernel_launch(void* const* d_in, const int* in_sizes, int n_in,
                              void* d_out, int out_size, void* d_ws, size_t ws_size,
                              hipStream_t stream) {
    const float* times = (const float*)d_in[0];
    // d_in[1] = coeff_a: unused by the reference vector field
    const float* cb = (const float*)d_in[2];
    const float* cc = (const float*)d_in[3];
    const float* cd = (const float*)d_in[4];
    const float* W1 = (const float*)d_in[5];
    const float* b1 = (const float*)d_in[6];
    const float* W2 = (const float*)d_in[7];
    const float* b2 = (const float*)d_in[8];
    const float* Wl = (const float*)d_in[9];
    const float* bl = (const float*)d_in[10];
    float* out = (float*)d_out;

    hipLaunchKernelGGL(cde_rk4_kernel, dim3(B_TOT / NB), dim3(WG), 0, stream,
                       times, cb, cc, cd, W1, b1, W2, b2, Wl, bl, out);
}

// Round 5
// 3621.795 us; speedup vs baseline: 6.7135x; 6.7135x over previous
//
#include <hip/hip_runtime.h>

// NeuralCDE RK4 — R5 bisect: R1's PASSED fp32-VALU structure, with ONLY
// phase-2 (h @ W2, 85% of FLOPs) replaced by bf16 3-way-split MFMA.
// Phase-1 (z @ W1 + tanh) stays fp32 VALU; z-state stays fp32 in LDS.
// Split: w = hh + hm + hl (bf16 each, exact to 2^-27, residuals always
// normal in bf16); per tile 6 MFMAs into one fp32 accumulator:
//   Ah*Bh + Ah*Bm + Am*Bh + Ah*Bl + Am*Bm + Al*Bh
// MFMA conventions = HW-verified m89/m120 mappings:
//   A[m=lane&15][k=quad*8+j], B[k=quad*8+j][n=lane&15], D[row=quad*4+r][col=lane&15]

typedef short short8 __attribute__((ext_vector_type(8)));
typedef float floatx4 __attribute__((ext_vector_type(4)));

constexpr int B_TOT  = 8192;
constexpr int L      = 256;
constexpr int CIN    = 6;
constexpr int H      = 32;
constexpr int MID    = 128;
constexpr int NSTEPS = L - 1;   // 255
constexpr int NB     = 16;      // batches per WG (one 16-row M tile)
constexpr int WG     = 256;     // 4 waves
// grid = B_TOT/NB = 512 -> 2 blocks/CU

constexpr int HP  = 144;   // h split row stride (shorts): 288 B/row, 16B-aligned;
                           // A-read b128 banks: 18*l15+q distinct mod 32 -> 2-way (free)
constexpr int GP  = 200;   // G row stride (fp32)
constexpr int ZP  = 33;    // fp32 z rows (odd -> conflict-free scalar)

__device__ __forceinline__ short f2bf(float x) {     // RNE fp32 -> bf16 bits
    unsigned u = __builtin_bit_cast(unsigned, x);
    unsigned r = (u + 0x7FFFu + ((u >> 16) & 1u)) >> 16;
    return (short)r;
}
__device__ __forceinline__ float bf2f(short b) {
    unsigned u = ((unsigned)(unsigned short)b) << 16;
    return __builtin_bit_cast(float, u);
}

__global__ __launch_bounds__(WG, 2)
void cde_hybrid_kernel(const float* __restrict__ times,
                       const float* __restrict__ coeff_b,
                       const float* __restrict__ coeff_c,
                       const float* __restrict__ coeff_d,
                       const float* __restrict__ W1g,
                       const float* __restrict__ b1g,
                       const float* __restrict__ W2g,
                       const float* __restrict__ b2g,
                       const float* __restrict__ Wlg,
                       const float* __restrict__ blg,
                       float* __restrict__ out)
{
    __shared__ float sW1[H][MID];                       // 16 KB (phase-1 VALU)
    __shared__ float sB1[MID];
    __shared__ __align__(16) short sHh[NB][HP], sHm[NB][HP], sHl[NB][HP]; // 13.5 KB
    __shared__ float sG[NB][GP];                        // 12.5 KB
    __shared__ float sZb[NB][ZP], sZc[NB][ZP], sZa[NB][ZP]; // fp32 state
    __shared__ float sDx[3][NB][8];

    const int tid  = threadIdx.x;
    const int lane = tid & 63;
    const int wave = tid >> 6;      // 0..3
    const int l15  = lane & 15;
    const int q    = lane >> 4;     // 0..3
    const int b0   = blockIdx.x * NB;

    // phase-1 mapping (fp32 VALU, R1-style): thread owns (batch bl_, mid-group grp)
    const int bl_ = tid & 15;       // batch 0..15
    const int grp = tid >> 4;       // 0..15 -> mids grp*8 .. grp*8+7

    // ---- one-time: W2 fragments -> registers (bf16 hi/mid/lo) ----
    // wave covers N-tiles {3*wave .. 3*wave+2}; K covered by ks=0..3.
    short8 w2h[3][4], w2m[3][4], w2l[3][4];
    float b2v[3];
    #pragma unroll
    for (int f = 0; f < 3; ++f) {
        const int n = (wave * 3 + f) * 16 + l15;
        b2v[f] = b2g[n];
        #pragma unroll
        for (int ks = 0; ks < 4; ++ks) {
            #pragma unroll
            for (int j = 0; j < 8; ++j) {
                const float w = W2g[(ks * 32 + q * 8 + j) * (H * CIN) + n];
                const short hh = f2bf(w);        const float r1 = w - bf2f(hh);
                const short mm = f2bf(r1);       const float r2 = r1 - bf2f(mm);
                w2h[f][ks][j] = hh; w2m[f][ks][j] = mm; w2l[f][ks][j] = f2bf(r2);
            }
        }
    }

    // ---- one-time staging + init ----
    for (int i = tid; i < H * MID; i += WG) sW1[i >> 7][i & 127] = W1g[i];
    for (int i = tid; i < MID; i += WG)     sB1[i] = b1g[i];
    for (int i = tid; i < NB * ZP; i += WG) {
        (&sZb[0][0])[i] = 0.f; (&sZc[0][0])[i] = 0.f; (&sZa[0][0])[i] = 0.f;
    }
    __syncthreads();

    for (int t = 0; t < NSTEPS; ++t) {
        const float dt = times[t + 1] - times[t];
        if (tid < NB * CIN) {
            const int bb = tid / CIN, ii = tid - bb * CIN;
            const size_t off = ((size_t)(b0 + bb) * NSTEPS + t) * CIN + ii;
            const float vb = coeff_b[off], vc = coeff_c[off], vd = coeff_d[off];
            const float f1 = 0.5f * dt;
            sDx[0][bb][ii] = vb;                              // dX(0)
            sDx[1][bb][ii] = vb + vc * f1 + vd * f1 * f1;     // dX(dt/2)
            sDx[2][bb][ii] = vb + vc * dt + vd * dt * dt;     // dX(dt)
        }
        __syncthreads();

        #pragma unroll 1
        for (int s = 0; s < 4; ++s) {
            // ---------- phase 1 (fp32 VALU): h = tanh(z @ W1 + b1) ----------
            float acc1[8];
            #pragma unroll
            for (int p = 0; p < 8; ++p) acc1[p] = sB1[grp * 8 + p];
            #pragma unroll
            for (int j = 0; j < H; ++j) {
                const float zv = sZc[bl_][j];
                #pragma unroll
                for (int p = 0; p < 8; ++p) acc1[p] += zv * sW1[j][grp * 8 + p];
            }
            #pragma unroll
            for (int p = 0; p < 8; ++p) {
                const float e = __expf(2.f * acc1[p]);        // tanh
                const float h = 1.f - 2.f / (e + 1.f);
                const int mid = grp * 8 + p;
                const short hh = f2bf(h);   const float r1 = h - bf2f(hh);
                const short hm = f2bf(r1);  const float r2 = r1 - bf2f(hm);
                sHh[bl_][mid] = hh; sHm[bl_][mid] = hm; sHl[bl_][mid] = f2bf(r2);
            }
            __syncthreads();

            // ---------- phase 2 (MFMA): G = h @ W2 + b2, K=128 ----------
            floatx4 g[3];
            #pragma unroll
            for (int f = 0; f < 3; ++f) g[f] = floatx4{0.f, 0.f, 0.f, 0.f};
            #pragma unroll
            for (int ks = 0; ks < 4; ++ks) {
                const short8 ah = *(const short8*)&sHh[l15][ks * 32 + q * 8];
                const short8 am = *(const short8*)&sHm[l15][ks * 32 + q * 8];
                const short8 al = *(const short8*)&sHl[l15][ks * 32 + q * 8];
                #pragma unroll
                for (int f = 0; f < 3; ++f) {
                    g[f] = __builtin_amdgcn_mfma_f32_16x16x32_bf16(ah, w2h[f][ks], g[f], 0, 0, 0);
                    g[f] = __builtin_amdgcn_mfma_f32_16x16x32_bf16(ah, w2m[f][ks], g[f], 0, 0, 0);
                    g[f] = __builtin_amdgcn_mfma_f32_16x16x32_bf16(am, w2h[f][ks], g[f], 0, 0, 0);
                    g[f] = __builtin_amdgcn_mfma_f32_16x16x32_bf16(ah, w2l[f][ks], g[f], 0, 0, 0);
                    g[f] = __builtin_amdgcn_mfma_f32_16x16x32_bf16(am, w2m[f][ks], g[f], 0, 0, 0);
                    g[f] = __builtin_amdgcn_mfma_f32_16x16x32_bf16(al, w2h[f][ks], g[f], 0, 0, 0);
                }
            }
            #pragma unroll
            for (int f = 0; f < 3; ++f) {
                const int col = (wave * 3 + f) * 16 + l15;
                #pragma unroll
                for (int r = 0; r < 4; ++r)
                    sG[q * 4 + r][col] = g[f][r] + b2v[f];
            }
            __syncthreads();

            // ---------- contraction k = G . dx, RK4 update ----------
            const int dsel = (s == 0) ? 0 : ((s == 3) ? 2 : 1);
            const float ws = (s == 0 || s == 3) ? dt * (1.f / 6.f) : dt * (1.f / 3.f);
            #pragma unroll
            for (int jj = 0; jj < 2; ++jj) {
                const int pp = tid + 256 * jj;
                const int b = pp >> 5, o = pp & 31;     // 16 batches x 32 outputs
                float k = 0.f;
                #pragma unroll
                for (int i = 0; i < 6; ++i)
                    k += sG[b][o * 6 + i] * sDx[dsel][b][i];
                const float za = sZa[b][o] + ws * k;
                sZa[b][o] = za;
                float zc;
                if (s < 3) {
                    zc = sZb[b][o] + ((s == 2) ? dt : 0.5f * dt) * k;
                } else {
                    sZb[b][o] = za;
                    zc = za;
                }
                sZc[b][o] = zc;
            }
            __syncthreads();
        }
    }

    // ---------- readout: out = zT @ Wl + bl ----------
    if (tid < NB * CIN) {
        const int bb = tid / CIN, c = tid - bb * CIN;
        float acc = blg[c];
        #pragma unroll
        for (int o = 0; o < H; ++o) acc += sZb[bb][o] * Wlg[o * CIN + c];
        out[(size_t)(b0 + bb) * CIN + c] = acc;
    }
}

extern "C" void kernel_launch(void* const* d_in, const int* in_sizes, int n_in,
                              void* d_out, int out_size, void* d_ws, size_t ws_size,
                              hipStream_t stream) {
    const float* times = (const float*)d_in[0];
    // d_in[1] = coeff_a: unused by the reference vector field
    const float* cb = (const float*)d_in[2];
    const float* cc = (const float*)d_in[3];
    const float* cd = (const float*)d_in[4];
    const float* W1 = (const float*)d_in[5];
    const float* b1 = (const float*)d_in[6];
    const float* W2 = (const float*)d_in[7];
    const float* b2 = (const float*)d_in[8];
    const float* Wl = (const float*)d_in[9];
    const float* bl = (const float*)d_in[10];
    float* out = (float*)d_out;

    hipLaunchKernelGGL(cde_hybrid_kernel, dim3(B_TOT / NB), dim3(WG), 0, stream,
                       times, cb, cc, cd, W1, b1, W2, b2, Wl, bl, out);
}